// Round 1
// baseline (453.622 us; speedup 1.0000x reference)
//
#include <hip/hip_runtime.h>

#define DF 128          // feature dim (fixed by problem)
#define BN 32           // nodes per block in the GEMM kernel
#define STR 133         // LDS row stride: banks for n0={0,8,16,24} differ by 8 -> conflict-free

// ---------------------------------------------------------------------------
// Kernel B: scatter-add of x[src] rows into sum[dst], plus degree counts.
// 32 lanes per edge; lane handles dwords {lane, lane+32, lane+64, lane+96}
// so each of the 4 atomic instructions is a contiguous 128B segment per row.
// ---------------------------------------------------------------------------
__global__ __launch_bounds__(256) void sage_scatter(
    const float* __restrict__ x, const int* __restrict__ src,
    const int* __restrict__ dst, float* __restrict__ sum,
    float* __restrict__ deg, int E)
{
    int tid = blockIdx.x * 256 + threadIdx.x;
    int e = tid >> 5;
    if (e >= E) return;
    int lane = tid & 31;
    int s = src[e];
    int d = dst[e];
    const float* xr = x + (size_t)s * DF;
    float* sr = sum + (size_t)d * DF;
    if (lane == 0) unsafeAtomicAdd(deg + d, 1.0f);
    float v0 = xr[lane];
    float v1 = xr[lane + 32];
    float v2 = xr[lane + 64];
    float v3 = xr[lane + 96];
    unsafeAtomicAdd(sr + lane,      v0);
    unsafeAtomicAdd(sr + lane + 32, v1);
    unsafeAtomicAdd(sr + lane + 64, v2);
    unsafeAtomicAdd(sr + lane + 96, v3);
}

// ---------------------------------------------------------------------------
// Kernel C: out[n] = x[n] + relu( (sum[n]/max(deg,1)) @ W_l + b_l + x[n] @ W_r )
// Block = 128 threads, 32 nodes/block. Thread t: cols c=(t%32)*4, nodes
// n0=(t/32)*8 .. +7  -> 8x4 fp32 accumulator, W float4 loads reused across
// the 8 nodes (16 KB of W traffic per node instead of 128 KB).
// sum lives in `out` (in-place): rows are staged to LDS before overwrite.
// ---------------------------------------------------------------------------
__global__ __launch_bounds__(128) void sage_gemm(
    const float* __restrict__ x, const float* __restrict__ Wl,
    const float* __restrict__ bl, const float* __restrict__ Wr,
    const float* __restrict__ deg, float* __restrict__ out, int N)
{
    __shared__ float xs[BN * STR];
    __shared__ float ms[BN * STR];
    const int t = threadIdx.x;
    const int nb = blockIdx.x * BN;

    // stage x rows and mean rows (one full row per iteration, coalesced)
    for (int r = 0; r < BN; ++r) {
        int n = nb + r;
        float xv = 0.f, sv = 0.f, dv = 1.f;
        if (n < N) {
            xv = x[(size_t)n * DF + t];
            sv = out[(size_t)n * DF + t];
            dv = fmaxf(deg[n], 1.0f);
        }
        xs[r * STR + t] = xv;
        ms[r * STR + t] = sv / dv;
    }
    __syncthreads();

    const int cg = t & 31;
    const int ng = t >> 5;
    const int c  = cg * 4;
    const int n0 = ng * 8;

    float acc[8][4];
    #pragma unroll
    for (int m = 0; m < 8; ++m)
        #pragma unroll
        for (int i = 0; i < 4; ++i) acc[m][i] = 0.f;

    #pragma unroll 4
    for (int k = 0; k < DF; ++k) {
        const float4 wl = *(const float4*)&Wl[k * DF + c];
        const float4 wr = *(const float4*)&Wr[k * DF + c];
        #pragma unroll
        for (int m = 0; m < 8; ++m) {
            const float xv = xs[(n0 + m) * STR + k];
            const float mv = ms[(n0 + m) * STR + k];
            acc[m][0] += mv * wl.x + xv * wr.x;
            acc[m][1] += mv * wl.y + xv * wr.y;
            acc[m][2] += mv * wl.z + xv * wr.z;
            acc[m][3] += mv * wl.w + xv * wr.w;
        }
    }

    const float4 blv = *(const float4*)&bl[c];
    #pragma unroll
    for (int m = 0; m < 8; ++m) {
        int n = nb + n0 + m;
        if (n < N) {
            float4 o;
            o.x = xs[(n0 + m) * STR + c + 0] + fmaxf(acc[m][0] + blv.x, 0.f);
            o.y = xs[(n0 + m) * STR + c + 1] + fmaxf(acc[m][1] + blv.y, 0.f);
            o.z = xs[(n0 + m) * STR + c + 2] + fmaxf(acc[m][2] + blv.z, 0.f);
            o.w = xs[(n0 + m) * STR + c + 3] + fmaxf(acc[m][3] + blv.w, 0.f);
            *(float4*)&out[(size_t)n * DF + c] = o;
        }
    }
}

extern "C" void kernel_launch(void* const* d_in, const int* in_sizes, int n_in,
                              void* d_out, int out_size, void* d_ws, size_t ws_size,
                              hipStream_t stream) {
    const float* x  = (const float*)d_in[0];
    const int*   ei = (const int*)d_in[1];
    const float* Wl = (const float*)d_in[2];
    const float* bl = (const float*)d_in[3];
    const float* Wr = (const float*)d_in[4];
    float* out = (float*)d_out;

    const int N = in_sizes[0] / DF;
    const int E = in_sizes[1] / 2;
    float* deg = (float*)d_ws;          // N floats = 200 KB

    // zero the sum accumulator (d_out) and degree array
    hipMemsetAsync(out, 0, (size_t)N * DF * sizeof(float), stream);
    hipMemsetAsync(deg, 0, (size_t)N * sizeof(float), stream);

    const int sthreads = E * 32;
    sage_scatter<<<(sthreads + 255) / 256, 256, 0, stream>>>(
        x, ei, ei + E, out, deg, E);

    sage_gemm<<<(N + BN - 1) / BN, 128, 0, stream>>>(
        x, Wl, bl, Wr, deg, out, N);
}

// Round 2
// 365.481 us; speedup vs baseline: 1.2412x; 1.2412x over previous
//
#include <hip/hip_runtime.h>

#define DF 128          // feature dim (fixed by problem)
#define BN 32           // nodes per block in the GEMM kernel
#define STR 132         // LDS row stride: multiple of 4 for ds_read_b128 alignment

// ---------------------------------------------------------------------------
// Kernel 1: histogram of dst into cnt[] (becomes offsets after scan)
// ---------------------------------------------------------------------------
__global__ __launch_bounds__(256) void sage_hist(
    const int* __restrict__ dst, int* __restrict__ cnt, int E)
{
    int e = blockIdx.x * 256 + threadIdx.x;
    if (e < E) atomicAdd(&cnt[dst[e]], 1);
}

// ---------------------------------------------------------------------------
// Kernel 2: single-block exclusive scan of cnt[0..N) in place -> off[],
// also writes a mutable cursor copy cur[], and off[N] = E.
// 1024 threads, each handles a serial chunk; Hillis-Steele over chunk totals.
// ---------------------------------------------------------------------------
__global__ __launch_bounds__(1024) void sage_scan(
    int* __restrict__ off, int* __restrict__ cur, int N, int E)
{
    __shared__ int sdata[1024];
    const int t = threadIdx.x;
    const int chunk = (N + 1023) / 1024;
    const int lo = t * chunk;
    const int hi = min(lo + chunk, N);

    int total = 0;
    for (int i = lo; i < hi; ++i) total += off[i];
    sdata[t] = total;
    __syncthreads();

    for (int s = 1; s < 1024; s <<= 1) {
        int v = (t >= s) ? sdata[t - s] : 0;
        __syncthreads();
        sdata[t] += v;
        __syncthreads();
    }

    int running = (t > 0) ? sdata[t - 1] : 0;
    for (int i = lo; i < hi; ++i) {
        int c = off[i];
        off[i] = running;
        cur[i] = running;
        running += c;
    }
    if (t == 0) off[N] = E;
}

// ---------------------------------------------------------------------------
// Kernel 3: counting-sort scatter of src indices by dst bucket.
// ---------------------------------------------------------------------------
__global__ __launch_bounds__(256) void sage_sort(
    const int* __restrict__ src, const int* __restrict__ dst,
    int* __restrict__ cur, int* __restrict__ srt, int E)
{
    int e = blockIdx.x * 256 + threadIdx.x;
    if (e < E) {
        int p = atomicAdd(&cur[dst[e]], 1);
        srt[p] = src[e];
    }
}

// ---------------------------------------------------------------------------
// Kernel 4: per-node gather + mean. 32 lanes per node; lane owns cols
// lane*4..lane*4+3 (one float4 per edge row -> 512B coalesced per group).
// Writes mean[n] into out[] (consumed in-place by the GEMM kernel).
// ---------------------------------------------------------------------------
__global__ __launch_bounds__(256) void sage_gather(
    const float* __restrict__ x, const int* __restrict__ off,
    const int* __restrict__ srt, float* __restrict__ out, int N)
{
    int tid = blockIdx.x * 256 + threadIdx.x;
    int n = tid >> 5;
    if (n >= N) return;
    int lane = tid & 31;

    int start = off[n];
    int end   = off[n + 1];
    int deg   = end - start;

    float a0 = 0.f, a1 = 0.f, a2 = 0.f, a3 = 0.f;
    for (int base = start; base < end; base += 32) {
        int cnt = min(32, end - base);
        int myidx = (lane < cnt) ? srt[base + lane] : 0;
        for (int j = 0; j < cnt; ++j) {
            int s = __shfl(myidx, j, 32);
            const float4 v = *(const float4*)&x[(size_t)s * DF + lane * 4];
            a0 += v.x; a1 += v.y; a2 += v.z; a3 += v.w;
        }
    }

    float inv = 1.0f / (float)max(deg, 1);
    float4 o;
    o.x = a0 * inv; o.y = a1 * inv; o.z = a2 * inv; o.w = a3 * inv;
    *(float4*)&out[(size_t)n * DF + lane * 4] = o;
}

// ---------------------------------------------------------------------------
// Kernel 5: out[n] = x[n] + relu( mean[n] @ W_l + b_l + x[n] @ W_r )
// mean lives in out[] (in-place; staged to LDS before overwrite).
// Block = 128 threads, 32 nodes. Thread t: cols c=(t%32)*4, nodes
// n0=(t/32)*8..+7. k-loop steps by 4 using ds_read_b128; LDS reads are
// uniform per half-wave (broadcast).
// ---------------------------------------------------------------------------
__global__ __launch_bounds__(128) void sage_gemm(
    const float* __restrict__ x, const float* __restrict__ Wl,
    const float* __restrict__ bl, const float* __restrict__ Wr,
    float* __restrict__ out, int N)
{
    __shared__ float xs[BN * STR];
    __shared__ float ms[BN * STR];
    const int t = threadIdx.x;
    const int nb = blockIdx.x * BN;

    for (int r = 0; r < BN; ++r) {
        int n = nb + r;
        float xv = 0.f, mv = 0.f;
        if (n < N) {
            xv = x[(size_t)n * DF + t];
            mv = out[(size_t)n * DF + t];
        }
        xs[r * STR + t] = xv;
        ms[r * STR + t] = mv;
    }
    __syncthreads();

    const int cg = t & 31;
    const int ng = t >> 5;
    const int c  = cg * 4;
    const int n0 = ng * 8;

    float acc[8][4];
    #pragma unroll
    for (int m = 0; m < 8; ++m)
        #pragma unroll
        for (int i = 0; i < 4; ++i) acc[m][i] = 0.f;

    for (int k0 = 0; k0 < DF; k0 += 4) {
        float4 wl[4], wr[4];
        #pragma unroll
        for (int j = 0; j < 4; ++j) {
            wl[j] = *(const float4*)&Wl[(k0 + j) * DF + c];
            wr[j] = *(const float4*)&Wr[(k0 + j) * DF + c];
        }
        #pragma unroll
        for (int m = 0; m < 8; ++m) {
            const float4 xv = *(const float4*)&xs[(n0 + m) * STR + k0];
            const float4 mv = *(const float4*)&ms[(n0 + m) * STR + k0];
            acc[m][0] += mv.x * wl[0].x + xv.x * wr[0].x
                       + mv.y * wl[1].x + xv.y * wr[1].x
                       + mv.z * wl[2].x + xv.z * wr[2].x
                       + mv.w * wl[3].x + xv.w * wr[3].x;
            acc[m][1] += mv.x * wl[0].y + xv.x * wr[0].y
                       + mv.y * wl[1].y + xv.y * wr[1].y
                       + mv.z * wl[2].y + xv.z * wr[2].y
                       + mv.w * wl[3].y + xv.w * wr[3].y;
            acc[m][2] += mv.x * wl[0].z + xv.x * wr[0].z
                       + mv.y * wl[1].z + xv.y * wr[1].z
                       + mv.z * wl[2].z + xv.z * wr[2].z
                       + mv.w * wl[3].z + xv.w * wr[3].z;
            acc[m][3] += mv.x * wl[0].w + xv.x * wr[0].w
                       + mv.y * wl[1].w + xv.y * wr[1].w
                       + mv.z * wl[2].w + xv.z * wr[2].w
                       + mv.w * wl[3].w + xv.w * wr[3].w;
        }
    }

    const float4 blv = *(const float4*)&bl[c];
    #pragma unroll
    for (int m = 0; m < 8; ++m) {
        int n = nb + n0 + m;
        if (n < N) {
            float4 o;
            o.x = xs[(n0 + m) * STR + c + 0] + fmaxf(acc[m][0] + blv.x, 0.f);
            o.y = xs[(n0 + m) * STR + c + 1] + fmaxf(acc[m][1] + blv.y, 0.f);
            o.z = xs[(n0 + m) * STR + c + 2] + fmaxf(acc[m][2] + blv.z, 0.f);
            o.w = xs[(n0 + m) * STR + c + 3] + fmaxf(acc[m][3] + blv.w, 0.f);
            *(float4*)&out[(size_t)n * DF + c] = o;
        }
    }
}

extern "C" void kernel_launch(void* const* d_in, const int* in_sizes, int n_in,
                              void* d_out, int out_size, void* d_ws, size_t ws_size,
                              hipStream_t stream) {
    const float* x  = (const float*)d_in[0];
    const int*   ei = (const int*)d_in[1];
    const float* Wl = (const float*)d_in[2];
    const float* bl = (const float*)d_in[3];
    const float* Wr = (const float*)d_in[4];
    float* out = (float*)d_out;

    const int N = in_sizes[0] / DF;
    const int E = in_sizes[1] / 2;
    const int* src = ei;
    const int* dst = ei + E;

    // workspace layout: off[N+1] | cur[N] | srt[E]   (~2.9 MB)
    int* off = (int*)d_ws;
    int* cur = off + (N + 1);
    int* srt = cur + N;

    hipMemsetAsync(off, 0, (size_t)(N + 1) * sizeof(int), stream);

    sage_hist<<<(E + 255) / 256, 256, 0, stream>>>(dst, off, E);
    sage_scan<<<1, 1024, 0, stream>>>(off, cur, N, E);
    sage_sort<<<(E + 255) / 256, 256, 0, stream>>>(src, dst, cur, srt, E);
    sage_gather<<<(N * 32 + 255) / 256, 256, 0, stream>>>(x, off, srt, out, N);
    sage_gemm<<<(N + BN - 1) / BN, 128, 0, stream>>>(x, Wl, bl, Wr, out, N);
}

// Round 3
// 267.525 us; speedup vs baseline: 1.6956x; 1.3662x over previous
//
#include <hip/hip_runtime.h>

#define DF 128          // feature dim (fixed by problem)
#define BN 32           // nodes per block in the GEMM kernel
#define STR 132         // LDS row stride: multiple of 4 for ds_read_b128 alignment
#define SCAN_B 64       // blocks in hierarchical scan
#define SCAN_T 256      // threads per scan block

// ---------------------------------------------------------------------------
// Kernel 1: histogram of dst into cnt[] (becomes offsets after scan)
// ---------------------------------------------------------------------------
__global__ __launch_bounds__(256) void sage_hist(
    const int* __restrict__ dst, int* __restrict__ cnt, int E)
{
    int e = blockIdx.x * 256 + threadIdx.x;
    if (e < E) atomicAdd(&cnt[dst[e]], 1);
}

// ---------------------------------------------------------------------------
// Hierarchical scan, pass 1: per-block reduce of cnt chunks -> blktot[]
// ---------------------------------------------------------------------------
__global__ __launch_bounds__(SCAN_T) void scan_reduce(
    const int* __restrict__ cnt, int* __restrict__ blktot, int N)
{
    __shared__ int sdata[SCAN_T];
    const int t = threadIdx.x;
    const int b = blockIdx.x;
    const int chunk = (N + SCAN_B * SCAN_T - 1) / (SCAN_B * SCAN_T);
    const int lo = (b * SCAN_T + t) * chunk;
    const int hi = min(lo + chunk, N);
    int total = 0;
    for (int i = lo; i < hi; ++i) total += cnt[i];
    sdata[t] = total;
    __syncthreads();
    for (int s = SCAN_T / 2; s > 0; s >>= 1) {
        if (t < s) sdata[t] += sdata[t + s];
        __syncthreads();
    }
    if (t == 0) blktot[b] = sdata[0];
}

// ---------------------------------------------------------------------------
// Hierarchical scan, pass 2: single small block exclusive-scans blktot[]
// ---------------------------------------------------------------------------
__global__ __launch_bounds__(SCAN_B) void scan_top(
    int* __restrict__ blktot)
{
    __shared__ int sdata[SCAN_B];
    const int t = threadIdx.x;
    sdata[t] = blktot[t];
    __syncthreads();
    for (int s = 1; s < SCAN_B; s <<= 1) {
        int v = (t >= s) ? sdata[t - s] : 0;
        __syncthreads();
        sdata[t] += v;
        __syncthreads();
    }
    blktot[t] = (t > 0) ? sdata[t - 1] : 0;   // exclusive
}

// ---------------------------------------------------------------------------
// Hierarchical scan, pass 3: write exclusive scan into off[] and cur[]
// ---------------------------------------------------------------------------
__global__ __launch_bounds__(SCAN_T) void scan_write(
    int* __restrict__ off, int* __restrict__ cur,
    const int* __restrict__ blktot, int N, int E)
{
    __shared__ int sdata[SCAN_T];
    const int t = threadIdx.x;
    const int b = blockIdx.x;
    const int chunk = (N + SCAN_B * SCAN_T - 1) / (SCAN_B * SCAN_T);
    const int lo = (b * SCAN_T + t) * chunk;
    const int hi = min(lo + chunk, N);

    int total = 0;
    for (int i = lo; i < hi; ++i) total += off[i];
    sdata[t] = total;
    __syncthreads();
    for (int s = 1; s < SCAN_T; s <<= 1) {
        int v = (t >= s) ? sdata[t - s] : 0;
        __syncthreads();
        sdata[t] += v;
        __syncthreads();
    }
    int running = blktot[b] + ((t > 0) ? sdata[t - 1] : 0);
    for (int i = lo; i < hi; ++i) {
        int c = off[i];
        off[i] = running;
        cur[i] = running;
        running += c;
    }
    if (b == 0 && t == 0) off[N] = E;
}

// ---------------------------------------------------------------------------
// Kernel 3: counting-sort scatter of src indices by dst bucket.
// ---------------------------------------------------------------------------
__global__ __launch_bounds__(256) void sage_sort(
    const int* __restrict__ src, const int* __restrict__ dst,
    int* __restrict__ cur, int* __restrict__ srt, int E)
{
    int e = blockIdx.x * 256 + threadIdx.x;
    if (e < E) {
        int p = atomicAdd(&cur[dst[e]], 1);
        srt[p] = src[e];
    }
}

// ---------------------------------------------------------------------------
// Kernel 4: per-node gather + mean. 32 lanes per node; lane owns cols
// lane*4..lane*4+3 (one float4 per edge row -> 512B coalesced per group).
// Writes mean[n] into out[] (consumed in-place by the GEMM kernel).
// ---------------------------------------------------------------------------
__global__ __launch_bounds__(256) void sage_gather(
    const float* __restrict__ x, const int* __restrict__ off,
    const int* __restrict__ srt, float* __restrict__ out, int N)
{
    int tid = blockIdx.x * 256 + threadIdx.x;
    int n = tid >> 5;
    if (n >= N) return;
    int lane = tid & 31;

    int start = off[n];
    int end   = off[n + 1];
    int deg   = end - start;

    float a0 = 0.f, a1 = 0.f, a2 = 0.f, a3 = 0.f;
    for (int base = start; base < end; base += 32) {
        int cnt = min(32, end - base);
        int myidx = (lane < cnt) ? srt[base + lane] : 0;
        for (int j = 0; j < cnt; ++j) {
            int s = __shfl(myidx, j, 32);
            const float4 v = *(const float4*)&x[(size_t)s * DF + lane * 4];
            a0 += v.x; a1 += v.y; a2 += v.z; a3 += v.w;
        }
    }

    float inv = 1.0f / (float)max(deg, 1);
    float4 o;
    o.x = a0 * inv; o.y = a1 * inv; o.z = a2 * inv; o.w = a3 * inv;
    *(float4*)&out[(size_t)n * DF + lane * 4] = o;
}

// ---------------------------------------------------------------------------
// Kernel 5: out[n] = x[n] + relu( mean[n] @ W_l + b_l + x[n] @ W_r )
// mean lives in out[] (in-place; staged to LDS before overwrite).
// ---------------------------------------------------------------------------
__global__ __launch_bounds__(128) void sage_gemm(
    const float* __restrict__ x, const float* __restrict__ Wl,
    const float* __restrict__ bl, const float* __restrict__ Wr,
    float* __restrict__ out, int N)
{
    __shared__ float xs[BN * STR];
    __shared__ float ms[BN * STR];
    const int t = threadIdx.x;
    const int nb = blockIdx.x * BN;

    for (int r = 0; r < BN; ++r) {
        int n = nb + r;
        float xv = 0.f, mv = 0.f;
        if (n < N) {
            xv = x[(size_t)n * DF + t];
            mv = out[(size_t)n * DF + t];
        }
        xs[r * STR + t] = xv;
        ms[r * STR + t] = mv;
    }
    __syncthreads();

    const int cg = t & 31;
    const int ng = t >> 5;
    const int c  = cg * 4;
    const int n0 = ng * 8;

    float acc[8][4];
    #pragma unroll
    for (int m = 0; m < 8; ++m)
        #pragma unroll
        for (int i = 0; i < 4; ++i) acc[m][i] = 0.f;

    for (int k0 = 0; k0 < DF; k0 += 4) {
        float4 wl[4], wr[4];
        #pragma unroll
        for (int j = 0; j < 4; ++j) {
            wl[j] = *(const float4*)&Wl[(k0 + j) * DF + c];
            wr[j] = *(const float4*)&Wr[(k0 + j) * DF + c];
        }
        #pragma unroll
        for (int m = 0; m < 8; ++m) {
            const float4 xv = *(const float4*)&xs[(n0 + m) * STR + k0];
            const float4 mv = *(const float4*)&ms[(n0 + m) * STR + k0];
            acc[m][0] += mv.x * wl[0].x + xv.x * wr[0].x
                       + mv.y * wl[1].x + xv.y * wr[1].x
                       + mv.z * wl[2].x + xv.z * wr[2].x
                       + mv.w * wl[3].x + xv.w * wr[3].x;
            acc[m][1] += mv.x * wl[0].y + xv.x * wr[0].y
                       + mv.y * wl[1].y + xv.y * wr[1].y
                       + mv.z * wl[2].y + xv.z * wr[2].y
                       + mv.w * wl[3].y + xv.w * wr[3].y;
            acc[m][2] += mv.x * wl[0].z + xv.x * wr[0].z
                       + mv.y * wl[1].z + xv.y * wr[1].z
                       + mv.z * wl[2].z + xv.z * wr[2].z
                       + mv.w * wl[3].z + xv.w * wr[3].z;
            acc[m][3] += mv.x * wl[0].w + xv.x * wr[0].w
                       + mv.y * wl[1].w + xv.y * wr[1].w
                       + mv.z * wl[2].w + xv.z * wr[2].w
                       + mv.w * wl[3].w + xv.w * wr[3].w;
        }
    }

    const float4 blv = *(const float4*)&bl[c];
    #pragma unroll
    for (int m = 0; m < 8; ++m) {
        int n = nb + n0 + m;
        if (n < N) {
            float4 o;
            o.x = xs[(n0 + m) * STR + c + 0] + fmaxf(acc[m][0] + blv.x, 0.f);
            o.y = xs[(n0 + m) * STR + c + 1] + fmaxf(acc[m][1] + blv.y, 0.f);
            o.z = xs[(n0 + m) * STR + c + 2] + fmaxf(acc[m][2] + blv.z, 0.f);
            o.w = xs[(n0 + m) * STR + c + 3] + fmaxf(acc[m][3] + blv.w, 0.f);
            *(float4*)&out[(size_t)n * DF + c] = o;
        }
    }
}

extern "C" void kernel_launch(void* const* d_in, const int* in_sizes, int n_in,
                              void* d_out, int out_size, void* d_ws, size_t ws_size,
                              hipStream_t stream) {
    const float* x  = (const float*)d_in[0];
    const int*   ei = (const int*)d_in[1];
    const float* Wl = (const float*)d_in[2];
    const float* bl = (const float*)d_in[3];
    const float* Wr = (const float*)d_in[4];
    float* out = (float*)d_out;

    const int N = in_sizes[0] / DF;
    const int E = in_sizes[1] / 2;
    const int* src = ei;
    const int* dst = ei + E;

    // workspace layout: off[N+1] | cur[N] | srt[E] | blktot[SCAN_B]
    int* off    = (int*)d_ws;
    int* cur    = off + (N + 1);
    int* srt    = cur + N;
    int* blktot = srt + E;

    hipMemsetAsync(off, 0, (size_t)(N + 1) * sizeof(int), stream);

    sage_hist<<<(E + 255) / 256, 256, 0, stream>>>(dst, off, E);
    scan_reduce<<<SCAN_B, SCAN_T, 0, stream>>>(off, blktot, N);
    scan_top<<<1, SCAN_B, 0, stream>>>(blktot);
    scan_write<<<SCAN_B, SCAN_T, 0, stream>>>(off, cur, blktot, N, E);
    sage_sort<<<(E + 255) / 256, 256, 0, stream>>>(src, dst, cur, srt, E);
    sage_gather<<<(N * 32 + 255) / 256, 256, 0, stream>>>(x, off, srt, out, N);
    sage_gemm<<<(N + BN - 1) / BN, 128, 0, stream>>>(x, Wl, bl, Wr, out, N);
}

// Round 4
// 212.533 us; speedup vs baseline: 2.1344x; 1.2587x over previous
//
#include <hip/hip_runtime.h>

#define DF 128
#define SCAN_B 64
#define SCAN_T 256

typedef __attribute__((ext_vector_type(8))) short short8;
typedef __attribute__((ext_vector_type(4))) float float4v;

__device__ __forceinline__ unsigned int bf16rne(float f) {
    unsigned int u = __float_as_uint(f);
    return (u + 0x7fffu + ((u >> 16) & 1u)) >> 16;
}
__device__ __forceinline__ float bf16lo(unsigned int w) {   // low 16 bits -> fp32
    return __uint_as_float(w << 16);
}
__device__ __forceinline__ float bf16hi(unsigned int w) {   // high 16 bits -> fp32
    return __uint_as_float(w & 0xffff0000u);
}

// ---------------------------------------------------------------------------
// histogram of dst
// ---------------------------------------------------------------------------
__global__ __launch_bounds__(256) void sage_hist(
    const int* __restrict__ dst, int* __restrict__ cnt, int E)
{
    int e = blockIdx.x * 256 + threadIdx.x;
    if (e < E) atomicAdd(&cnt[dst[e]], 1);
}

// ---------------------------------------------------------------------------
// hierarchical scan (3 passes)
// ---------------------------------------------------------------------------
__global__ __launch_bounds__(SCAN_T) void scan_reduce(
    const int* __restrict__ cnt, int* __restrict__ blktot, int N)
{
    __shared__ int sdata[SCAN_T];
    const int t = threadIdx.x, b = blockIdx.x;
    const int chunk = (N + SCAN_B * SCAN_T - 1) / (SCAN_B * SCAN_T);
    const int lo = (b * SCAN_T + t) * chunk;
    const int hi = min(lo + chunk, N);
    int total = 0;
    for (int i = lo; i < hi; ++i) total += cnt[i];
    sdata[t] = total;
    __syncthreads();
    for (int s = SCAN_T / 2; s > 0; s >>= 1) {
        if (t < s) sdata[t] += sdata[t + s];
        __syncthreads();
    }
    if (t == 0) blktot[b] = sdata[0];
}

__global__ __launch_bounds__(SCAN_B) void scan_top(int* __restrict__ blktot)
{
    __shared__ int sdata[SCAN_B];
    const int t = threadIdx.x;
    sdata[t] = blktot[t];
    __syncthreads();
    for (int s = 1; s < SCAN_B; s <<= 1) {
        int v = (t >= s) ? sdata[t - s] : 0;
        __syncthreads();
        sdata[t] += v;
        __syncthreads();
    }
    blktot[t] = (t > 0) ? sdata[t - 1] : 0;
}

__global__ __launch_bounds__(SCAN_T) void scan_write(
    int* __restrict__ off, int* __restrict__ cur,
    const int* __restrict__ blktot, int N, int E)
{
    __shared__ int sdata[SCAN_T];
    const int t = threadIdx.x, b = blockIdx.x;
    const int chunk = (N + SCAN_B * SCAN_T - 1) / (SCAN_B * SCAN_T);
    const int lo = (b * SCAN_T + t) * chunk;
    const int hi = min(lo + chunk, N);
    int total = 0;
    for (int i = lo; i < hi; ++i) total += off[i];
    sdata[t] = total;
    __syncthreads();
    for (int s = 1; s < SCAN_T; s <<= 1) {
        int v = (t >= s) ? sdata[t - s] : 0;
        __syncthreads();
        sdata[t] += v;
        __syncthreads();
    }
    int running = blktot[b] + ((t > 0) ? sdata[t - 1] : 0);
    for (int i = lo; i < hi; ++i) {
        int c = off[i];
        off[i] = running;
        cur[i] = running;
        running += c;
    }
    if (b == 0 && t == 0) off[N] = E;
}

// ---------------------------------------------------------------------------
// counting-sort of src by dst bucket
// ---------------------------------------------------------------------------
__global__ __launch_bounds__(256) void sage_sort(
    const int* __restrict__ src, const int* __restrict__ dst,
    int* __restrict__ cur, int* __restrict__ srt, int E)
{
    int e = blockIdx.x * 256 + threadIdx.x;
    if (e < E) {
        int p = atomicAdd(&cur[dst[e]], 1);
        srt[p] = src[e];
    }
}

// ---------------------------------------------------------------------------
// xcast: x fp32 -> bf16, written into the xb half of the concat rows.
// Row n layout (bf16, 512 B): [ meanb(128) | xb(128) ].  rowb = d_out.
// 16 threads per row, each converts 8 elements -> one uint4 store.
// ---------------------------------------------------------------------------
__global__ __launch_bounds__(256) void sage_xcast(
    const float* __restrict__ x, char* __restrict__ rowb, int N)
{
    int tid = blockIdx.x * 256 + threadIdx.x;
    if (tid >= N * 16) return;
    int n = tid >> 4;
    int c = (tid & 15) * 8;
    const float4* xp = (const float4*)&x[(size_t)n * DF + c];
    float4 a = xp[0], b = xp[1];
    uint4 o;
    o.x = bf16rne(a.x) | (bf16rne(a.y) << 16);
    o.y = bf16rne(a.z) | (bf16rne(a.w) << 16);
    o.z = bf16rne(b.x) | (bf16rne(b.y) << 16);
    o.w = bf16rne(b.z) | (bf16rne(b.w) << 16);
    *(uint4*)(rowb + (size_t)n * 512 + 256 + c * 2) = o;
}

// ---------------------------------------------------------------------------
// bprep: swizzle [Wl;Wr] (256x128 fp32) into MFMA B-fragment order, bf16.
// Frag (ks, ct): lane l holds B[ks*32 + (l>>4)*8 + j][ct*16 + (l&15)], j=0..7.
// Bf index: ((ks*8 + ct)*64 + lane) * 16 bytes.
// ---------------------------------------------------------------------------
__global__ __launch_bounds__(256) void sage_bprep(
    const float* __restrict__ Wl, const float* __restrict__ Wr,
    uint4* __restrict__ Bf)
{
    int tid = blockIdx.x * 256 + threadIdx.x;   // 0..4095
    int lane = tid & 63;
    int ctks = tid >> 6;
    int ks = ctks >> 3, ct = ctks & 7;
    int q = lane >> 4, m16 = lane & 15;
    int n = ct * 16 + m16;
    unsigned int w[4];
    #pragma unroll
    for (int p = 0; p < 4; ++p) {
        int k0 = ks * 32 + q * 8 + p * 2;
        float f0 = (k0 < DF) ? Wl[k0 * DF + n] : Wr[(k0 - DF) * DF + n];
        float f1 = (k0 + 1 < DF) ? Wl[(k0 + 1) * DF + n] : Wr[(k0 + 1 - DF) * DF + n];
        w[p] = bf16rne(f0) | (bf16rne(f1) << 16);
    }
    uint4 o = {w[0], w[1], w[2], w[3]};
    Bf[tid] = o;
}

// ---------------------------------------------------------------------------
// gather: per-node mean of bf16 x rows. 16 lanes per node; lane owns 8 cols.
// Reads xb half of rowb for src nodes; writes meanb half for its own node.
// (disjoint halves -> no hazard across concurrent blocks)
// ---------------------------------------------------------------------------
__global__ __launch_bounds__(256) void sage_gather(
    const char* __restrict__ rowb_r, char* __restrict__ rowb_w,
    const int* __restrict__ off, const int* __restrict__ srt, int N)
{
    int tid = blockIdx.x * 256 + threadIdx.x;
    int n = tid >> 4;
    if (n >= N) return;
    int ln = tid & 15;

    int start = off[n];
    int end   = off[n + 1];
    int deg   = end - start;

    float a[8];
    #pragma unroll
    for (int i = 0; i < 8; ++i) a[i] = 0.f;

    for (int e = start; e < end; ++e) {
        int s = srt[e];                         // same addr across 16 lanes
        uint4 v = *(const uint4*)(rowb_r + (size_t)s * 512 + 256 + ln * 16);
        a[0] += bf16lo(v.x); a[1] += bf16hi(v.x);
        a[2] += bf16lo(v.y); a[3] += bf16hi(v.y);
        a[4] += bf16lo(v.z); a[5] += bf16hi(v.z);
        a[6] += bf16lo(v.w); a[7] += bf16hi(v.w);
    }

    float inv = 1.0f / (float)max(deg, 1);
    uint4 o;
    o.x = bf16rne(a[0] * inv) | (bf16rne(a[1] * inv) << 16);
    o.y = bf16rne(a[2] * inv) | (bf16rne(a[3] * inv) << 16);
    o.z = bf16rne(a[4] * inv) | (bf16rne(a[5] * inv) << 16);
    o.w = bf16rne(a[6] * inv) | (bf16rne(a[7] * inv) << 16);
    *(uint4*)(rowb_w + (size_t)n * 512 + ln * 16) = o;
}

// ---------------------------------------------------------------------------
// gemm: out[n] = x[n] + relu( [meanb|xb][n] (1x256) @ Bf (256x128) + bl )
// MFMA 16x16x32 bf16. Block = 256 threads = 4 waves, 16 nodes/wave, no LDS.
// A-frags read from rowb (= d_out, in place); C written as fp32 over the
// same rows (each wave touches only its own 16 rows; loads precede stores).
// ---------------------------------------------------------------------------
__global__ __launch_bounds__(256) void sage_gemm(
    const char* __restrict__ rowb, const uint4* __restrict__ Bf,
    const float* __restrict__ x, const float* __restrict__ bl,
    float* __restrict__ out, int N)
{
    const int t = threadIdx.x;
    const int w = t >> 6;
    const int lane = t & 63;
    const int q = lane >> 4;
    const int m16 = lane & 15;
    const int nb = blockIdx.x * 64 + w * 16;

    // A row pointer (clamped for tail block; results discarded by store guard)
    const int am = min(nb + m16, N - 1);
    const short8* arow = (const short8*)(rowb + (size_t)am * 512);
    const short8* bfp = (const short8*)Bf;

    float4v acc[8];
    #pragma unroll
    for (int ct = 0; ct < 8; ++ct) acc[ct] = (float4v){0.f, 0.f, 0.f, 0.f};

    #pragma unroll
    for (int ks = 0; ks < 8; ++ks) {
        short8 afrag = arow[ks * 4 + q];
        #pragma unroll
        for (int ct = 0; ct < 8; ++ct) {
            short8 bfrag = bfp[(ks * 8 + ct) * 64 + lane];
            acc[ct] = __builtin_amdgcn_mfma_f32_16x16x32_bf16(afrag, bfrag, acc[ct], 0, 0, 0);
        }
    }

    // epilogue: C row = q*4 + r, col = ct*16 + m16
    #pragma unroll
    for (int ct = 0; ct < 8; ++ct) {
        int col = ct * 16 + m16;
        float b = bl[col];
        #pragma unroll
        for (int r = 0; r < 4; ++r) {
            int n2 = nb + q * 4 + r;
            if (n2 < N) {
                size_t idx = (size_t)n2 * DF + col;
                out[idx] = x[idx] + fmaxf(acc[ct][r] + b, 0.f);
            }
        }
    }
}

extern "C" void kernel_launch(void* const* d_in, const int* in_sizes, int n_in,
                              void* d_out, int out_size, void* d_ws, size_t ws_size,
                              hipStream_t stream) {
    const float* x  = (const float*)d_in[0];
    const int*   ei = (const int*)d_in[1];
    const float* Wl = (const float*)d_in[2];
    const float* bl = (const float*)d_in[3];
    const float* Wr = (const float*)d_in[4];
    float* out = (float*)d_out;
    char* rowb = (char*)d_out;          // concat bf16 rows live in d_out

    const int N = in_sizes[0] / DF;
    const int E = in_sizes[1] / 2;
    const int* src = ei;
    const int* dst = ei + E;

    // ws layout: off[N+1] | cur[N] | srt[E] | blktot[64] | pad | Bf[4096 uint4]
    int* off    = (int*)d_ws;
    int* cur    = off + (N + 1);
    int* srt    = cur + N;
    int* blktot = srt + E;
    size_t bfoff = ((size_t)(N + 1 + N + E + 64) * 4 + 15) & ~(size_t)15;
    uint4* Bf   = (uint4*)((char*)d_ws + bfoff);

    hipMemsetAsync(off, 0, (size_t)(N + 1) * sizeof(int), stream);

    sage_hist<<<(E + 255) / 256, 256, 0, stream>>>(dst, off, E);
    scan_reduce<<<SCAN_B, SCAN_T, 0, stream>>>(off, blktot, N);
    scan_top<<<1, SCAN_B, 0, stream>>>(blktot);
    scan_write<<<SCAN_B, SCAN_T, 0, stream>>>(off, cur, blktot, N, E);
    sage_xcast<<<(N * 16 + 255) / 256, 256, 0, stream>>>(x, rowb, N);
    sage_bprep<<<16, 256, 0, stream>>>(Wl, Wr, Bf);
    sage_sort<<<(E + 255) / 256, 256, 0, stream>>>(src, dst, cur, srt, E);
    sage_gather<<<(N * 16 + 255) / 256, 256, 0, stream>>>(rowb, rowb, off, srt, N);
    sage_gemm<<<(N + 63) / 64, 256, 0, stream>>>(rowb, Bf, x, bl, out, N);
}